// Round 7
// baseline (57.449 us; speedup 1.0000x reference)
//
#include <hip/hip_runtime.h>

#define HD 1024           // hidden dim D
#define D4 (HD/4)         // float4s per row = 256
#define GBLK 2048         // phase-1 blocks: 8/CU -> 32 waves/CU (A/B vs 1024)

// Kernel 1: partial column-reduction, contiguous-chunk row assignment.
// Block b owns rows [b*rpb, (b+1)*rpb) -- a strictly sequential 128 KB
// stream. 8-row unroll -> 8 float4 loads in flight per thread; grad[r..r+7]
// is a uniform contiguous scalar fetch. G=2048 doubles resident waves to
// hide HBM latency (round-6 analysis: 5.4 TB/s demand w/ only 3.2 TB/s HBM
// => latency-limited, not BW-limited).
__global__ void __launch_bounds__(256) partial_reduce(
        const float* __restrict__ past,   // [N, HD]
        const float* __restrict__ grad,   // [N]
        float* __restrict__ partials,     // [G, HD]
        int N, int G) {
    const int b = blockIdx.x;
    const int t = threadIdx.x;            // 0..255
    const float4* past4 = (const float4*)past;
    const int rpb = N / G;                // rows per block (32)
    const int r0 = b * rpb;
    const int rend = r0 + rpb;
    float4 a0 = make_float4(0.f, 0.f, 0.f, 0.f);
    float4 a1 = make_float4(0.f, 0.f, 0.f, 0.f);
    float4 a2 = make_float4(0.f, 0.f, 0.f, 0.f);
    float4 a3 = make_float4(0.f, 0.f, 0.f, 0.f);
    int r = r0;
    for (; r + 8 <= rend; r += 8) {
        const float g0 = grad[r + 0];     // uniform, contiguous scalar loads
        const float g1 = grad[r + 1];
        const float g2 = grad[r + 2];
        const float g3 = grad[r + 3];
        const float g4 = grad[r + 4];
        const float g5 = grad[r + 5];
        const float g6 = grad[r + 6];
        const float g7 = grad[r + 7];
        const float4 v0 = past4[(size_t)(r + 0) * D4 + t];  // coalesced
        const float4 v1 = past4[(size_t)(r + 1) * D4 + t];
        const float4 v2 = past4[(size_t)(r + 2) * D4 + t];
        const float4 v3 = past4[(size_t)(r + 3) * D4 + t];
        const float4 v4 = past4[(size_t)(r + 4) * D4 + t];
        const float4 v5 = past4[(size_t)(r + 5) * D4 + t];
        const float4 v6 = past4[(size_t)(r + 6) * D4 + t];
        const float4 v7 = past4[(size_t)(r + 7) * D4 + t];
        a0.x += g0 * v0.x; a0.y += g0 * v0.y; a0.z += g0 * v0.z; a0.w += g0 * v0.w;
        a1.x += g1 * v1.x; a1.y += g1 * v1.y; a1.z += g1 * v1.z; a1.w += g1 * v1.w;
        a2.x += g2 * v2.x; a2.y += g2 * v2.y; a2.z += g2 * v2.z; a2.w += g2 * v2.w;
        a3.x += g3 * v3.x; a3.y += g3 * v3.y; a3.z += g3 * v3.z; a3.w += g3 * v3.w;
        a0.x += g4 * v4.x; a0.y += g4 * v4.y; a0.z += g4 * v4.z; a0.w += g4 * v4.w;
        a1.x += g5 * v5.x; a1.y += g5 * v5.y; a1.z += g5 * v5.z; a1.w += g5 * v5.w;
        a2.x += g6 * v6.x; a2.y += g6 * v6.y; a2.z += g6 * v6.z; a2.w += g6 * v6.w;
        a3.x += g7 * v7.x; a3.y += g7 * v7.y; a3.z += g7 * v7.z; a3.w += g7 * v7.w;
    }
    for (; r < rend; ++r) {               // tail (empty when rpb % 8 == 0)
        const float g = grad[r];
        const float4 v = past4[(size_t)r * D4 + t];
        a0.x += g * v.x; a0.y += g * v.y; a0.z += g * v.z; a0.w += g * v.w;
    }
    a0.x += a1.x + a2.x + a3.x;
    a0.y += a1.y + a2.y + a3.y;
    a0.z += a1.z + a2.z + a3.z;
    a0.w += a1.w + a2.w + a3.w;
    ((float4*)partials)[(size_t)b * D4 + t] = a0;      // coalesced 16B/lane
}

// Kernel 2 (unchanged, proven): fused final-reduce + outer product.
__global__ void __launch_bounds__(256) finish_outer(
        const float* __restrict__ partials,  // [G, HD]
        const float* __restrict__ cur,       // [HD]
        float* __restrict__ out,             // [HD, HD]
        int G) {
    __shared__ float lds[16];
    __shared__ float wrow[4];
    const int t = threadIdx.x;               // 0..255
    const int R = blockIdx.x * 4;            // first output row of this block
    const int c = R + (t & 3);               // partials column this lane sums
    float acc = 0.f;
    for (int g = (t >> 2); g < G; g += 64)
        acc += partials[(size_t)g * HD + c]; // L2/L3-resident
    acc += __shfl_xor(acc, 4);
    acc += __shfl_xor(acc, 8);
    acc += __shfl_xor(acc, 16);
    acc += __shfl_xor(acc, 32);
    const int lane = t & 63, wave = t >> 6;
    if (lane < 4) lds[wave * 4 + lane] = acc;
    __syncthreads();
    if (t < 4) wrow[t] = lds[t] + lds[4 + t] + lds[8 + t] + lds[12 + t];
    __syncthreads();
    const float4 cv = ((const float4*)cur)[t];          // L2-hot
    #pragma unroll
    for (int j = 0; j < 4; ++j) {
        const float w = wrow[j];
        float4 o;
        o.x = w * cv.x; o.y = w * cv.y; o.z = w * cv.z; o.w = w * cv.w;
        ((float4*)out)[(size_t)(R + j) * D4 + t] = o;   // coalesced 16B/lane
    }
}

extern "C" void kernel_launch(void* const* d_in, const int* in_sizes, int n_in,
                              void* d_out, int out_size, void* d_ws, size_t ws_size,
                              hipStream_t stream) {
    const float* past = (const float*)d_in[0];   // [N, 1024] fp32
    const float* cur  = (const float*)d_in[1];   // [1024] fp32
    const float* grad = (const float*)d_in[2];   // [N] fp32
    float* out = (float*)d_out;                  // [1024, 1024] fp32
    const int N = in_sizes[2];                   // 65536

    float* partials = (float*)d_ws;              // [G, 1024] floats (8 MB)

    int G = GBLK;                                // 8 blocks/CU -> 32 waves/CU
    const size_t avail_floats = ws_size / sizeof(float);
    if ((size_t)G * HD > avail_floats) {
        G = (int)(avail_floats / HD);
        if (G < 1) G = 1;
    }

    partial_reduce<<<G, 256, 0, stream>>>(past, grad, partials, N, G);
    finish_outer<<<HD / 4, 256, 0, stream>>>(partials, cur, out, G);
}

// Round 9
// 49.985 us; speedup vs baseline: 1.1493x; 1.1493x over previous
//
#include <hip/hip_runtime.h>

#define HD 1024           // hidden dim D
#define D4 (HD/4)         // float4s per row = 256
#define GBLK 512          // phase-1 blocks: 2/CU -> 8 waves/CU, 512KB streams

typedef float floatx4 __attribute__((ext_vector_type(4)));  // nontemporal-OK

// Kernel 1: partial column-reduction, contiguous-chunk row assignment.
// A/B vs round 6: G 1024 -> 512. Block b owns rows [b*rpb, (b+1)*rpb) --
// a strictly sequential 512 KB stream (rpb=128, 16 iters of 8-row unroll).
// Trend (G=2048 regressed twice) says fewer/longer streams win; 8 waves/CU
// x 8 KB in flight = 64 KB/CU, still 3x the ~22 KB BW*latency product.
__global__ void __launch_bounds__(256) partial_reduce(
        const float* __restrict__ past,   // [N, HD]
        const float* __restrict__ grad,   // [N]
        float* __restrict__ partials,     // [G, HD]
        int N, int G) {
    const int b = blockIdx.x;
    const int t = threadIdx.x;            // 0..255
    const float4* past4 = (const float4*)past;
    const int rpb = N / G;                // rows per block (128)
    const int r0 = b * rpb;
    const int rend = r0 + rpb;
    float4 a0 = make_float4(0.f, 0.f, 0.f, 0.f);
    float4 a1 = make_float4(0.f, 0.f, 0.f, 0.f);
    float4 a2 = make_float4(0.f, 0.f, 0.f, 0.f);
    float4 a3 = make_float4(0.f, 0.f, 0.f, 0.f);
    int r = r0;
    for (; r + 8 <= rend; r += 8) {
        const float g0 = grad[r + 0];     // uniform, contiguous scalar loads
        const float g1 = grad[r + 1];
        const float g2 = grad[r + 2];
        const float g3 = grad[r + 3];
        const float g4 = grad[r + 4];
        const float g5 = grad[r + 5];
        const float g6 = grad[r + 6];
        const float g7 = grad[r + 7];
        const float4 v0 = past4[(size_t)(r + 0) * D4 + t];  // coalesced
        const float4 v1 = past4[(size_t)(r + 1) * D4 + t];
        const float4 v2 = past4[(size_t)(r + 2) * D4 + t];
        const float4 v3 = past4[(size_t)(r + 3) * D4 + t];
        const float4 v4 = past4[(size_t)(r + 4) * D4 + t];
        const float4 v5 = past4[(size_t)(r + 5) * D4 + t];
        const float4 v6 = past4[(size_t)(r + 6) * D4 + t];
        const float4 v7 = past4[(size_t)(r + 7) * D4 + t];
        a0.x += g0 * v0.x; a0.y += g0 * v0.y; a0.z += g0 * v0.z; a0.w += g0 * v0.w;
        a1.x += g1 * v1.x; a1.y += g1 * v1.y; a1.z += g1 * v1.z; a1.w += g1 * v1.w;
        a2.x += g2 * v2.x; a2.y += g2 * v2.y; a2.z += g2 * v2.z; a2.w += g2 * v2.w;
        a3.x += g3 * v3.x; a3.y += g3 * v3.y; a3.z += g3 * v3.z; a3.w += g3 * v3.w;
        a0.x += g4 * v4.x; a0.y += g4 * v4.y; a0.z += g4 * v4.z; a0.w += g4 * v4.w;
        a1.x += g5 * v5.x; a1.y += g5 * v5.y; a1.z += g5 * v5.z; a1.w += g5 * v5.w;
        a2.x += g6 * v6.x; a2.y += g6 * v6.y; a2.z += g6 * v6.z; a2.w += g6 * v6.w;
        a3.x += g7 * v7.x; a3.y += g7 * v7.y; a3.z += g7 * v7.z; a3.w += g7 * v7.w;
    }
    for (; r < rend; ++r) {               // tail (empty when rpb % 8 == 0)
        const float g = grad[r];
        const float4 v = past4[(size_t)r * D4 + t];
        a0.x += g * v.x; a0.y += g * v.y; a0.z += g * v.z; a0.w += g * v.w;
    }
    a0.x += a1.x + a2.x + a3.x;
    a0.y += a1.y + a2.y + a3.y;
    a0.z += a1.z + a2.z + a3.z;
    a0.w += a1.w + a2.w + a3.w;
    ((float4*)partials)[(size_t)b * D4 + t] = a0;      // coalesced 16B/lane
}

// Kernel 2: fused final-reduce + outer product (structure proven).
// out written with non-temporal stores (ext_vector type): written once,
// never re-read by us; keeps past-lines resident in L3 across replays.
__global__ void __launch_bounds__(256) finish_outer(
        const float* __restrict__ partials,  // [G, HD]
        const float* __restrict__ cur,       // [HD]
        float* __restrict__ out,             // [HD, HD]
        int G) {
    __shared__ float lds[16];
    __shared__ float wrow[4];
    const int t = threadIdx.x;               // 0..255
    const int R = blockIdx.x * 4;            // first output row of this block
    const int c = R + (t & 3);               // partials column this lane sums
    float acc = 0.f;
    for (int g = (t >> 2); g < G; g += 64)
        acc += partials[(size_t)g * HD + c]; // L2/L3-resident
    acc += __shfl_xor(acc, 4);
    acc += __shfl_xor(acc, 8);
    acc += __shfl_xor(acc, 16);
    acc += __shfl_xor(acc, 32);
    const int lane = t & 63, wave = t >> 6;
    if (lane < 4) lds[wave * 4 + lane] = acc;
    __syncthreads();
    if (t < 4) wrow[t] = lds[t] + lds[4 + t] + lds[8 + t] + lds[12 + t];
    __syncthreads();
    const float4 cv = ((const float4*)cur)[t];          // L2-hot
    #pragma unroll
    for (int j = 0; j < 4; ++j) {
        const float w = wrow[j];
        floatx4 o;
        o.x = w * cv.x; o.y = w * cv.y; o.z = w * cv.z; o.w = w * cv.w;
        __builtin_nontemporal_store(o, (floatx4*)out + (size_t)(R + j) * D4 + t);
    }
}

extern "C" void kernel_launch(void* const* d_in, const int* in_sizes, int n_in,
                              void* d_out, int out_size, void* d_ws, size_t ws_size,
                              hipStream_t stream) {
    const float* past = (const float*)d_in[0];   // [N, 1024] fp32
    const float* cur  = (const float*)d_in[1];   // [1024] fp32
    const float* grad = (const float*)d_in[2];   // [N] fp32
    float* out = (float*)d_out;                  // [1024, 1024] fp32
    const int N = in_sizes[2];                   // 65536

    float* partials = (float*)d_ws;              // [G, 1024] floats (2 MB)

    int G = GBLK;                                // 2 blocks/CU -> 8 waves/CU
    const size_t avail_floats = ws_size / sizeof(float);
    if ((size_t)G * HD > avail_floats) {
        G = (int)(avail_floats / HD);
        if (G < 1) G = 1;
    }

    partial_reduce<<<G, 256, 0, stream>>>(past, grad, partials, N, G);
    finish_outer<<<HD / 4, 256, 0, stream>>>(partials, cur, out, G);
}

// Round 10
// 47.015 us; speedup vs baseline: 1.2219x; 1.0632x over previous
//
#include <hip/hip_runtime.h>

#define HD 1024           // hidden dim D
#define D4 (HD/4)         // float4s per row = 256
#define GBLK 256          // phase-1 blocks: 1/CU -> 4 waves/CU, 1MB streams

typedef float floatx4 __attribute__((ext_vector_type(4)));  // nontemporal-OK

// Kernel 1: partial column-reduction, contiguous-chunk row assignment.
// G sweep: 2048->57.4us, 1024->52.95, 512->49.98. Single-variable A/B:
// G=256 (rpb=256, 1MB sequential stream/block, 32 iters of 8-row unroll).
// In-flight 4 waves x 8 x 16B x 64 lanes = 64KB/CU, ~3x the BW*latency
// product, so latency hiding should hold while stream count halves again.
__global__ void __launch_bounds__(256) partial_reduce(
        const float* __restrict__ past,   // [N, HD]
        const float* __restrict__ grad,   // [N]
        float* __restrict__ partials,     // [G, HD]
        int N, int G) {
    const int b = blockIdx.x;
    const int t = threadIdx.x;            // 0..255
    const float4* past4 = (const float4*)past;
    const int rpb = N / G;                // rows per block (256)
    const int r0 = b * rpb;
    const int rend = r0 + rpb;
    float4 a0 = make_float4(0.f, 0.f, 0.f, 0.f);
    float4 a1 = make_float4(0.f, 0.f, 0.f, 0.f);
    float4 a2 = make_float4(0.f, 0.f, 0.f, 0.f);
    float4 a3 = make_float4(0.f, 0.f, 0.f, 0.f);
    int r = r0;
    for (; r + 8 <= rend; r += 8) {
        const float g0 = grad[r + 0];     // uniform, contiguous scalar loads
        const float g1 = grad[r + 1];
        const float g2 = grad[r + 2];
        const float g3 = grad[r + 3];
        const float g4 = grad[r + 4];
        const float g5 = grad[r + 5];
        const float g6 = grad[r + 6];
        const float g7 = grad[r + 7];
        const float4 v0 = past4[(size_t)(r + 0) * D4 + t];  // coalesced
        const float4 v1 = past4[(size_t)(r + 1) * D4 + t];
        const float4 v2 = past4[(size_t)(r + 2) * D4 + t];
        const float4 v3 = past4[(size_t)(r + 3) * D4 + t];
        const float4 v4 = past4[(size_t)(r + 4) * D4 + t];
        const float4 v5 = past4[(size_t)(r + 5) * D4 + t];
        const float4 v6 = past4[(size_t)(r + 6) * D4 + t];
        const float4 v7 = past4[(size_t)(r + 7) * D4 + t];
        a0.x += g0 * v0.x; a0.y += g0 * v0.y; a0.z += g0 * v0.z; a0.w += g0 * v0.w;
        a1.x += g1 * v1.x; a1.y += g1 * v1.y; a1.z += g1 * v1.z; a1.w += g1 * v1.w;
        a2.x += g2 * v2.x; a2.y += g2 * v2.y; a2.z += g2 * v2.z; a2.w += g2 * v2.w;
        a3.x += g3 * v3.x; a3.y += g3 * v3.y; a3.z += g3 * v3.z; a3.w += g3 * v3.w;
        a0.x += g4 * v4.x; a0.y += g4 * v4.y; a0.z += g4 * v4.z; a0.w += g4 * v4.w;
        a1.x += g5 * v5.x; a1.y += g5 * v5.y; a1.z += g5 * v5.z; a1.w += g5 * v5.w;
        a2.x += g6 * v6.x; a2.y += g6 * v6.y; a2.z += g6 * v6.z; a2.w += g6 * v6.w;
        a3.x += g7 * v7.x; a3.y += g7 * v7.y; a3.z += g7 * v7.z; a3.w += g7 * v7.w;
    }
    for (; r < rend; ++r) {               // tail (empty when rpb % 8 == 0)
        const float g = grad[r];
        const float4 v = past4[(size_t)r * D4 + t];
        a0.x += g * v.x; a0.y += g * v.y; a0.z += g * v.z; a0.w += g * v.w;
    }
    a0.x += a1.x + a2.x + a3.x;
    a0.y += a1.y + a2.y + a3.y;
    a0.z += a1.z + a2.z + a3.z;
    a0.w += a1.w + a2.w + a3.w;
    ((float4*)partials)[(size_t)b * D4 + t] = a0;      // coalesced 16B/lane
}

// Kernel 2: fused final-reduce + outer product (structure proven).
// out written with non-temporal stores: written once, never re-read by us;
// keeps past-lines resident in L3 across replays.
__global__ void __launch_bounds__(256) finish_outer(
        const float* __restrict__ partials,  // [G, HD]
        const float* __restrict__ cur,       // [HD]
        float* __restrict__ out,             // [HD, HD]
        int G) {
    __shared__ float lds[16];
    __shared__ float wrow[4];
    const int t = threadIdx.x;               // 0..255
    const int R = blockIdx.x * 4;            // first output row of this block
    const int c = R + (t & 3);               // partials column this lane sums
    float acc = 0.f;
    for (int g = (t >> 2); g < G; g += 64)
        acc += partials[(size_t)g * HD + c]; // L2/L3-resident
    acc += __shfl_xor(acc, 4);
    acc += __shfl_xor(acc, 8);
    acc += __shfl_xor(acc, 16);
    acc += __shfl_xor(acc, 32);
    const int lane = t & 63, wave = t >> 6;
    if (lane < 4) lds[wave * 4 + lane] = acc;
    __syncthreads();
    if (t < 4) wrow[t] = lds[t] + lds[4 + t] + lds[8 + t] + lds[12 + t];
    __syncthreads();
    const float4 cv = ((const float4*)cur)[t];          // L2-hot
    #pragma unroll
    for (int j = 0; j < 4; ++j) {
        const float w = wrow[j];
        floatx4 o;
        o.x = w * cv.x; o.y = w * cv.y; o.z = w * cv.z; o.w = w * cv.w;
        __builtin_nontemporal_store(o, (floatx4*)out + (size_t)(R + j) * D4 + t);
    }
}

extern "C" void kernel_launch(void* const* d_in, const int* in_sizes, int n_in,
                              void* d_out, int out_size, void* d_ws, size_t ws_size,
                              hipStream_t stream) {
    const float* past = (const float*)d_in[0];   // [N, 1024] fp32
    const float* cur  = (const float*)d_in[1];   // [1024] fp32
    const float* grad = (const float*)d_in[2];   // [N] fp32
    float* out = (float*)d_out;                  // [1024, 1024] fp32
    const int N = in_sizes[2];                   // 65536

    float* partials = (float*)d_ws;              // [G, 1024] floats (1 MB)

    int G = GBLK;                                // 1 block/CU -> 4 waves/CU
    const size_t avail_floats = ws_size / sizeof(float);
    if ((size_t)G * HD > avail_floats) {
        G = (int)(avail_floats / HD);
        if (G < 1) G = 1;
    }

    partial_reduce<<<G, 256, 0, stream>>>(past, grad, partials, N, G);
    finish_outer<<<HD / 4, 256, 0, stream>>>(partials, cur, out, G);
}